// Round 13
// baseline (194.618 us; speedup 1.0000x reference)
//
#include <hip/hip_runtime.h>

#define N_NODES 50000
#define D 128
#define N_EDGES 600000
#define BN_EPS 1e-5f
#define NREP 64       // stats replicas (contention spreading)
#define BUCKET 64     // max degree capacity (Binomial(600K,1/50K): P(>64)~0)

#define MLP_BLOCKS 512          // 2 blocks/CU persistent
#define N_GROUPS   3125         // 50000 / 16 rows per wave-group
#define MLP_WAVES  (MLP_BLOCKS * 4)

// prep_kernel block ranges
#define FEATC_BLOCKS 3125   // 800000 / 256
#define WPREP_BLOCKS 128    // 32768 / 256
#define ZERO_BLOCKS  260    // ceil((50000 + 16384)/256)

typedef __attribute__((ext_vector_type(8))) short short8;
typedef __attribute__((ext_vector_type(4))) float floatx4;

__device__ __forceinline__ unsigned f2bf(float f) {
    unsigned x = __float_as_uint(f);
    return (x + 0x7fffu + ((x >> 16) & 1u)) >> 16;  // RNE
}
__device__ __forceinline__ float bflo(unsigned v) { return __uint_as_float(v << 16); }
__device__ __forceinline__ float bfhi(unsigned v) { return __uint_as_float(v & 0xffff0000u); }

// ---------------------------------------------------------------------------
// Fused prep: featconv (fp32->bf16), weight transpose+convert, zero cnt/stats
// ---------------------------------------------------------------------------
__global__ void prep_kernel(const float* __restrict__ f, unsigned* __restrict__ fb,
                            const float* __restrict__ W1, const float* __restrict__ W2,
                            unsigned short* __restrict__ Wt1, unsigned short* __restrict__ Wt2,
                            int* __restrict__ cnt, float* __restrict__ stats) {
    int b = blockIdx.x;
    int tid = threadIdx.x;
    if (b < FEATC_BLOCKS) {
        int gid = b * 256 + tid;  // < 800000 exactly
        float4 a = ((const float4*)f)[gid * 2];
        float4 c = ((const float4*)f)[gid * 2 + 1];
        uint4 o;
        o.x = f2bf(a.x) | (f2bf(a.y) << 16);
        o.y = f2bf(a.z) | (f2bf(a.w) << 16);
        o.z = f2bf(c.x) | (f2bf(c.y) << 16);
        o.w = f2bf(c.z) | (f2bf(c.w) << 16);
        ((uint4*)fb)[gid] = o;
    } else if (b < FEATC_BLOCKS + WPREP_BLOCKS) {
        int gid = (b - FEATC_BLOCKS) * 256 + tid;  // < 32768
        int m = gid >> 14;
        int idx = gid & (D * D - 1);
        int k = idx >> 7;
        int n = idx & 127;
        const float* W = m ? W2 : W1;
        unsigned short* Wt = m ? Wt2 : Wt1;
        Wt[n * D + k] = (unsigned short)f2bf(W[k * D + n]);
    } else {
        int gid = (b - FEATC_BLOCKS - WPREP_BLOCKS) * 256 + tid;
        if (gid < N_NODES) cnt[gid] = 0;
        int sid = gid - N_NODES;
        if (sid >= 0 && sid < NREP * 256) stats[sid] = 0.f;
    }
}

// ---------------------------------------------------------------------------
// Bucket scatter: ssrc[dst*BUCKET + cnt[dst]++] = src (ushort).
// ---------------------------------------------------------------------------
__global__ void scatter_kernel(const int* __restrict__ ei,
                               int* __restrict__ cnt,
                               unsigned short* __restrict__ ssrc) {
    int e = blockIdx.x * blockDim.x + threadIdx.x;
    if (e >= N_EDGES) return;
    int src = ei[e];
    int dst = ei[N_EDGES + e];
    int pos = atomicAdd(&cnt[dst], 1);
    ssrc[dst * BUCKET + pos] = (unsigned short)src;
}

// ---------------------------------------------------------------------------
// Gather: h[n] = feat[n] + sum_{s in bucket(n)} feat[s].
// 4 nodes per wave, 16 lanes per node, uint4 (8 bf16 = 16B) per lane.
// ---------------------------------------------------------------------------
__global__ __launch_bounds__(256) void gather_kernel(const uint4* __restrict__ fb4,
                                                     const int* __restrict__ cnt,
                                                     const unsigned short* __restrict__ ssrc,
                                                     uint4* __restrict__ hb4) {
    int wave = (blockIdx.x * 256 + threadIdx.x) >> 6;
    int lane = threadIdx.x & 63;
    int quad = lane >> 4;
    int l16 = lane & 15;
    int node = wave * 4 + quad;   // 12500 waves * 4 = 50000 exactly
    int beg = node * BUCKET;
    int end = beg + cnt[node];

    float a0, a1, a2, a3, a4, a5, a6, a7;
    uint4 own = fb4[node * 16 + l16];
    a0 = bflo(own.x); a1 = bfhi(own.x);
    a2 = bflo(own.y); a3 = bfhi(own.y);
    a4 = bflo(own.z); a5 = bfhi(own.z);
    a6 = bflo(own.w); a7 = bfhi(own.w);

    int j = beg;
    for (; j + 3 < end; j += 4) {
        uint4 v0 = fb4[(int)ssrc[j] * 16 + l16];
        uint4 v1 = fb4[(int)ssrc[j + 1] * 16 + l16];
        uint4 v2 = fb4[(int)ssrc[j + 2] * 16 + l16];
        uint4 v3 = fb4[(int)ssrc[j + 3] * 16 + l16];
        a0 += (bflo(v0.x) + bflo(v1.x)) + (bflo(v2.x) + bflo(v3.x));
        a1 += (bfhi(v0.x) + bfhi(v1.x)) + (bfhi(v2.x) + bfhi(v3.x));
        a2 += (bflo(v0.y) + bflo(v1.y)) + (bflo(v2.y) + bflo(v3.y));
        a3 += (bfhi(v0.y) + bfhi(v1.y)) + (bfhi(v2.y) + bfhi(v3.y));
        a4 += (bflo(v0.z) + bflo(v1.z)) + (bflo(v2.z) + bflo(v3.z));
        a5 += (bfhi(v0.z) + bfhi(v1.z)) + (bfhi(v2.z) + bfhi(v3.z));
        a6 += (bflo(v0.w) + bflo(v1.w)) + (bflo(v2.w) + bflo(v3.w));
        a7 += (bfhi(v0.w) + bfhi(v1.w)) + (bfhi(v2.w) + bfhi(v3.w));
    }
    for (; j < end; ++j) {
        uint4 v = fb4[(int)ssrc[j] * 16 + l16];
        a0 += bflo(v.x); a1 += bfhi(v.x);
        a2 += bflo(v.y); a3 += bfhi(v.y);
        a4 += bflo(v.z); a5 += bfhi(v.z);
        a6 += bflo(v.w); a7 += bfhi(v.w);
    }

    uint4 o;
    o.x = f2bf(a0) | (f2bf(a1) << 16);
    o.y = f2bf(a2) | (f2bf(a3) << 16);
    o.z = f2bf(a4) | (f2bf(a5) << 16);
    o.w = f2bf(a6) | (f2bf(a7) << 16);
    hb4[node * 16 + l16] = o;
}

// ---------------------------------------------------------------------------
// Persistent-wave fused MLP: y = relu(relu(hb@W1+b1)@W2+b2) as packed bf16,
// + BN column partials in registers, flushed once per block.
//
// B fragments read straight from global: Wt1/Wt2 are 32KB each, L1/L2
// resident after first touch (no intra-group reuse justified LDS staging).
// LDS = 16KB wave-private h1 C->A exchange only; zero barriers in the loop
// (a wave's A-band is wave-private; per-wave LDS ordering is HW-guaranteed).
// ---------------------------------------------------------------------------
__global__ __launch_bounds__(256) void mlp_kernel(
    const unsigned short* __restrict__ A,
    const unsigned short* __restrict__ Bt1, const unsigned short* __restrict__ Bt2,
    const float* __restrict__ bias1, const float* __restrict__ bias2,
    unsigned short* __restrict__ yb, float* __restrict__ stats)
{
    __shared__ unsigned short Xch[4 * 16 * 128];  // 16KB: per-wave h1 exchange

    const int tid = threadIdx.x;
    const int lane = tid & 63;
    const int wid = tid >> 6;
    const int l15 = lane & 15;
    const int quad = lane >> 4;
    unsigned short* X = &Xch[wid * 2048];  // wave-private [16][128]

    float bs1[8], bs2[8];
    #pragma unroll
    for (int n = 0; n < 8; ++n) {
        bs1[n] = bias1[n * 16 + l15];
        bs2[n] = bias2[n * 16 + l15];
    }

    float s[8], q[8];
    #pragma unroll
    for (int n = 0; n < 8; ++n) { s[n] = 0.f; q[n] = 0.f; }

    const int gw = blockIdx.x * 4 + wid;   // global wave id, 0..2047
    for (int grp = gw; grp < N_GROUPS; grp += MLP_WAVES) {
        const int rowBase = grp * 16;      // 3125*16 = 50000, always in-bounds

        // ---- A fragments from global (coalesced, L2-hot after gather) ----
        short8 af[4];
        #pragma unroll
        for (int kc = 0; kc < 4; ++kc)
            af[kc] = *(const short8*)&A[(rowBase + l15) * 128 + kc * 32 + quad * 8];

        // ---- GEMM1, B-frags from global (L1-resident) ----
        floatx4 acc[8];
        #pragma unroll
        for (int n = 0; n < 8; ++n) acc[n] = (floatx4){0.f, 0.f, 0.f, 0.f};
        #pragma unroll
        for (int kc = 0; kc < 4; ++kc) {
            #pragma unroll
            for (int n = 0; n < 8; ++n) {
                short8 bf = *(const short8*)&Bt1[(n * 16 + l15) * 128 + kc * 32 + quad * 8];
                acc[n] = __builtin_amdgcn_mfma_f32_16x16x32_bf16(af[kc], bf, acc[n], 0, 0, 0);
            }
        }

        // ---- h1 C-layout -> A-layout via wave-private LDS (no barrier) ----
        #pragma unroll
        for (int n = 0; n < 8; ++n) {
            int col = n * 16 + l15;
            int gg = col >> 3;
            int o7 = col & 7;
            #pragma unroll
            for (int r = 0; r < 4; ++r) {
                int rl = quad * 4 + r;
                float v = fmaxf(acc[n][r] + bs1[n], 0.f);
                X[rl * 128 + ((gg ^ rl) * 8) + o7] = (unsigned short)f2bf(v);
            }
        }
        #pragma unroll
        for (int kc = 0; kc < 4; ++kc)
            af[kc] = *(const short8*)&X[l15 * 128 + (((kc * 4 + quad) ^ l15) * 8)];

        // ---- GEMM2 ----
        #pragma unroll
        for (int n = 0; n < 8; ++n) acc[n] = (floatx4){0.f, 0.f, 0.f, 0.f};
        #pragma unroll
        for (int kc = 0; kc < 4; ++kc) {
            #pragma unroll
            for (int n = 0; n < 8; ++n) {
                short8 bf = *(const short8*)&Bt2[(n * 16 + l15) * 128 + kc * 32 + quad * 8];
                acc[n] = __builtin_amdgcn_mfma_f32_16x16x32_bf16(af[kc], bf, acc[n], 0, 0, 0);
            }
        }

        // ---- ReLU + y store + BN partials ----
        #pragma unroll
        for (int n = 0; n < 8; ++n) {
            int col = n * 16 + l15;
            #pragma unroll
            for (int r = 0; r < 4; ++r) {
                int row = rowBase + quad * 4 + r;
                float v = fmaxf(acc[n][r] + bs2[n], 0.f);
                yb[row * 128 + col] = (unsigned short)f2bf(v);
                s[n] += v;
                q[n] += v * v;
            }
        }
    }

    // ---- flush BN partials: quad-reduce, block-reduce, one atomic set ----
    #pragma unroll
    for (int n = 0; n < 8; ++n) {
        s[n] += __shfl_xor(s[n], 16);
        s[n] += __shfl_xor(s[n], 32);
        q[n] += __shfl_xor(q[n], 16);
        q[n] += __shfl_xor(q[n], 32);
    }
    __syncthreads();  // all waves done with their Xch bands; reuse as scratch
    float* red = (float*)Xch;  // [0..511]=sums [512..1023]=sqs
    if (lane < 16) {
        #pragma unroll
        for (int n = 0; n < 8; ++n) {
            red[wid * 128 + n * 16 + lane] = s[n];
            red[512 + wid * 128 + n * 16 + lane] = q[n];
        }
    }
    __syncthreads();
    float* myStats = stats + (blockIdx.x & (NREP - 1)) * 256;
    if (tid < 128) {
        float ss = 0.f, qq = 0.f;
        #pragma unroll
        for (int w = 0; w < 4; ++w) {
            ss += red[w * 128 + tid];
            qq += red[512 + w * 128 + tid];
        }
        atomicAdd(&myStats[tid], ss);
        atomicAdd(&myStats[128 + tid], qq);
    }
}

// ---------------------------------------------------------------------------
// BatchNorm apply: reduce the 64 stats replicas in-block, precompute
// per-column scale/shift, then o = y*scale + shift. 4 uint4s per thread.
// ---------------------------------------------------------------------------
__global__ __launch_bounds__(256) void bn_kernel(const uint4* __restrict__ yb4,
                                                 float* __restrict__ out,
                                                 const float* __restrict__ stats,
                                                 const float* __restrict__ gamma,
                                                 const float* __restrict__ beta)
{
    __shared__ float red[256];
    __shared__ float sc[128], sh[128];
    int tid = threadIdx.x;

    float acc = 0.f;
    #pragma unroll 8
    for (int r = 0; r < NREP; ++r) acc += stats[r * 256 + tid];
    red[tid] = acc;
    __syncthreads();
    if (tid < 128) {
        const float inv_n = 1.0f / (float)N_NODES;
        float m = red[tid] * inv_n;
        float var = red[128 + tid] * inv_n - m * m;
        float scale = gamma[tid] * rsqrtf(var + BN_EPS);
        sc[tid] = scale;
        sh[tid] = beta[tid] - m * scale;
    }
    __syncthreads();

    const int n8 = N_NODES * D / 8;  // 800000 uint4s
    int base = (blockIdx.x * 256 + tid) * 4;
    #pragma unroll
    for (int i = 0; i < 4; ++i) {
        int idx = base + i;
        if (idx >= n8) break;
        int c0 = (idx << 3) & 127;
        uint4 v = yb4[idx];
        float4 o0, o1;
        o0.x = bflo(v.x) * sc[c0 + 0] + sh[c0 + 0];
        o0.y = bfhi(v.x) * sc[c0 + 1] + sh[c0 + 1];
        o0.z = bflo(v.y) * sc[c0 + 2] + sh[c0 + 2];
        o0.w = bfhi(v.y) * sc[c0 + 3] + sh[c0 + 3];
        o1.x = bflo(v.z) * sc[c0 + 4] + sh[c0 + 4];
        o1.y = bfhi(v.z) * sc[c0 + 5] + sh[c0 + 5];
        o1.z = bflo(v.w) * sc[c0 + 6] + sh[c0 + 6];
        o1.w = bfhi(v.w) * sc[c0 + 7] + sh[c0 + 7];
        ((float4*)out)[idx * 2] = o0;
        ((float4*)out)[idx * 2 + 1] = o1;
    }
}

// ---------------------------------------------------------------------------
extern "C" void kernel_launch(void* const* d_in, const int* in_sizes, int n_in,
                              void* d_out, int out_size, void* d_ws, size_t ws_size,
                              hipStream_t stream) {
    const float* feature = (const float*)d_in[0];
    const int*   ei      = (const int*)d_in[1];
    const float* W1      = (const float*)d_in[2];
    const float* b1      = (const float*)d_in[3];
    const float* W2      = (const float*)d_in[4];
    const float* b2      = (const float*)d_in[5];
    const float* gamma   = (const float*)d_in[6];
    const float* beta    = (const float*)d_in[7];
    float* out = (float*)d_out;

    unsigned*       featb = (unsigned*)d_ws;                        // 12.8 MB
    unsigned*       hb    = featb + N_NODES * 64;                   // 12.8 MB
    unsigned*       yb32  = hb + N_NODES * 64;                      // 12.8 MB
    unsigned short* Wt1   = (unsigned short*)(yb32 + N_NODES * 64); // 32 KB
    unsigned short* Wt2   = Wt1 + D * D;                            // 32 KB
    float*          stats = (float*)(Wt2 + D * D);                  // 64 KB
    int*            cnt   = (int*)(stats + NREP * 256);             // 200 KB
    unsigned short* ssrc  = (unsigned short*)(cnt + N_NODES);       // 6.4 MB buckets
    unsigned short* yb    = (unsigned short*)yb32;

    prep_kernel<<<FEATC_BLOCKS + WPREP_BLOCKS + ZERO_BLOCKS, 256, 0, stream>>>(
        feature, featb, W1, W2, Wt1, Wt2, cnt, stats);
    scatter_kernel<<<(N_EDGES + 255) / 256, 256, 0, stream>>>(ei, cnt, ssrc);
    gather_kernel<<<N_NODES / 4 * 64 / 256, 256, 0, stream>>>(
        (const uint4*)featb, cnt, ssrc, (uint4*)hb);
    mlp_kernel<<<MLP_BLOCKS, 256, 0, stream>>>(
        (const unsigned short*)hb, Wt1, Wt2, b1, b2, yb, stats);
    bn_kernel<<<(N_NODES * D / 8 / 4 + 255) / 256, 256, 0, stream>>>(
        (const uint4*)yb, out, stats, gamma, beta);
}

// Round 14
// 182.308 us; speedup vs baseline: 1.0675x; 1.0675x over previous
//
#include <hip/hip_runtime.h>

#define N_NODES 50000
#define D 128
#define N_EDGES 600000
#define BN_EPS 1e-5f
#define NREP 64       // stats replicas (contention spreading)
#define BUCKET 64     // max degree capacity (Binomial(600K,1/50K): P(>64)~0)

#define MLP_BLOCKS 512          // 2 blocks/CU persistent
#define N_GROUPS   3125         // 50000 / 16 rows per wave-group
#define MLP_WAVES  (MLP_BLOCKS * 4)

// prep_kernel block ranges
#define FEATC_BLOCKS 3125   // 800000 / 256
#define WPREP_BLOCKS 128    // 32768 / 256
#define ZERO_BLOCKS  260    // ceil((50000 + 16384)/256)

typedef __attribute__((ext_vector_type(8))) short short8;
typedef __attribute__((ext_vector_type(4))) float floatx4;

__device__ __forceinline__ unsigned f2bf(float f) {
    unsigned x = __float_as_uint(f);
    return (x + 0x7fffu + ((x >> 16) & 1u)) >> 16;  // RNE
}
__device__ __forceinline__ float bflo(unsigned v) { return __uint_as_float(v << 16); }
__device__ __forceinline__ float bfhi(unsigned v) { return __uint_as_float(v & 0xffff0000u); }

// ---------------------------------------------------------------------------
// Fused prep: featconv (fp32->bf16), weight transpose+convert, zero cnt/stats
// ---------------------------------------------------------------------------
__global__ void prep_kernel(const float* __restrict__ f, unsigned* __restrict__ fb,
                            const float* __restrict__ W1, const float* __restrict__ W2,
                            unsigned short* __restrict__ Wt1, unsigned short* __restrict__ Wt2,
                            int* __restrict__ cnt, float* __restrict__ stats) {
    int b = blockIdx.x;
    int tid = threadIdx.x;
    if (b < FEATC_BLOCKS) {
        int gid = b * 256 + tid;  // < 800000 exactly
        float4 a = ((const float4*)f)[gid * 2];
        float4 c = ((const float4*)f)[gid * 2 + 1];
        uint4 o;
        o.x = f2bf(a.x) | (f2bf(a.y) << 16);
        o.y = f2bf(a.z) | (f2bf(a.w) << 16);
        o.z = f2bf(c.x) | (f2bf(c.y) << 16);
        o.w = f2bf(c.z) | (f2bf(c.w) << 16);
        ((uint4*)fb)[gid] = o;
    } else if (b < FEATC_BLOCKS + WPREP_BLOCKS) {
        int gid = (b - FEATC_BLOCKS) * 256 + tid;  // < 32768
        int m = gid >> 14;
        int idx = gid & (D * D - 1);
        int k = idx >> 7;
        int n = idx & 127;
        const float* W = m ? W2 : W1;
        unsigned short* Wt = m ? Wt2 : Wt1;
        Wt[n * D + k] = (unsigned short)f2bf(W[k * D + n]);
    } else {
        int gid = (b - FEATC_BLOCKS - WPREP_BLOCKS) * 256 + tid;
        if (gid < N_NODES) cnt[gid] = 0;
        int sid = gid - N_NODES;
        if (sid >= 0 && sid < NREP * 256) stats[sid] = 0.f;
    }
}

// ---------------------------------------------------------------------------
// Bucket scatter: ssrc[dst*BUCKET + cnt[dst]++] = src (ushort).
// ---------------------------------------------------------------------------
__global__ void scatter_kernel(const int* __restrict__ ei,
                               int* __restrict__ cnt,
                               unsigned short* __restrict__ ssrc) {
    int e = blockIdx.x * blockDim.x + threadIdx.x;
    if (e >= N_EDGES) return;
    int src = ei[e];
    int dst = ei[N_EDGES + e];
    int pos = atomicAdd(&cnt[dst], 1);
    ssrc[dst * BUCKET + pos] = (unsigned short)src;
}

// ---------------------------------------------------------------------------
// Gather: h[n] = feat[n] + sum_{s in bucket(n)} feat[s].
// 4 nodes per wave, 16 lanes per node, uint4 (8 bf16 = 16B) per lane.
// ---------------------------------------------------------------------------
__global__ __launch_bounds__(256) void gather_kernel(const uint4* __restrict__ fb4,
                                                     const int* __restrict__ cnt,
                                                     const unsigned short* __restrict__ ssrc,
                                                     uint4* __restrict__ hb4) {
    int wave = (blockIdx.x * 256 + threadIdx.x) >> 6;
    int lane = threadIdx.x & 63;
    int quad = lane >> 4;
    int l16 = lane & 15;
    int node = wave * 4 + quad;   // 12500 waves * 4 = 50000 exactly
    int beg = node * BUCKET;
    int end = beg + cnt[node];

    float a0, a1, a2, a3, a4, a5, a6, a7;
    uint4 own = fb4[node * 16 + l16];
    a0 = bflo(own.x); a1 = bfhi(own.x);
    a2 = bflo(own.y); a3 = bfhi(own.y);
    a4 = bflo(own.z); a5 = bfhi(own.z);
    a6 = bflo(own.w); a7 = bfhi(own.w);

    int j = beg;
    for (; j + 3 < end; j += 4) {
        uint4 v0 = fb4[(int)ssrc[j] * 16 + l16];
        uint4 v1 = fb4[(int)ssrc[j + 1] * 16 + l16];
        uint4 v2 = fb4[(int)ssrc[j + 2] * 16 + l16];
        uint4 v3 = fb4[(int)ssrc[j + 3] * 16 + l16];
        a0 += (bflo(v0.x) + bflo(v1.x)) + (bflo(v2.x) + bflo(v3.x));
        a1 += (bfhi(v0.x) + bfhi(v1.x)) + (bfhi(v2.x) + bfhi(v3.x));
        a2 += (bflo(v0.y) + bflo(v1.y)) + (bflo(v2.y) + bflo(v3.y));
        a3 += (bfhi(v0.y) + bfhi(v1.y)) + (bfhi(v2.y) + bfhi(v3.y));
        a4 += (bflo(v0.z) + bflo(v1.z)) + (bflo(v2.z) + bflo(v3.z));
        a5 += (bfhi(v0.z) + bfhi(v1.z)) + (bfhi(v2.z) + bfhi(v3.z));
        a6 += (bflo(v0.w) + bflo(v1.w)) + (bflo(v2.w) + bflo(v3.w));
        a7 += (bfhi(v0.w) + bfhi(v1.w)) + (bfhi(v2.w) + bfhi(v3.w));
    }
    for (; j < end; ++j) {
        uint4 v = fb4[(int)ssrc[j] * 16 + l16];
        a0 += bflo(v.x); a1 += bfhi(v.x);
        a2 += bflo(v.y); a3 += bfhi(v.y);
        a4 += bflo(v.z); a5 += bfhi(v.z);
        a6 += bflo(v.w); a7 += bfhi(v.w);
    }

    uint4 o;
    o.x = f2bf(a0) | (f2bf(a1) << 16);
    o.y = f2bf(a2) | (f2bf(a3) << 16);
    o.z = f2bf(a4) | (f2bf(a5) << 16);
    o.w = f2bf(a6) | (f2bf(a7) << 16);
    hb4[node * 16 + l16] = o;
}

// ---------------------------------------------------------------------------
// Persistent-wave fused MLP: y = relu(relu(hb@W1+b1)@W2+b2) as packed bf16,
// + BN column partials accumulated in registers, flushed once per block.
//
// 512 blocks (2/CU, 80KB LDS). B1+B2 staged once, ONE barrier, then each of
// the 2048 waves grid-strides over 3125 16-row groups with NO synchronization:
// a wave's A-band is entirely wave-private (A-frag load from global, h1
// C->A-layout exchange through a per-wave 4KB LDS scratch -- per-wave LDS
// ordering is HW-guaranteed, no barrier needed).
// NOTE (R13): reading B-frags from global instead of LDS costs ~12us --
// keep the LDS staging.
// ---------------------------------------------------------------------------
__global__ __launch_bounds__(256) void mlp_kernel(
    const unsigned short* __restrict__ A,
    const unsigned short* __restrict__ Bt1, const unsigned short* __restrict__ Bt2,
    const float* __restrict__ bias1, const float* __restrict__ bias2,
    unsigned short* __restrict__ yb, float* __restrict__ stats)
{
    __shared__ unsigned short B1lds[128 * 128];   // 32KB
    __shared__ unsigned short B2lds[128 * 128];   // 32KB
    __shared__ unsigned short Xch[4 * 16 * 128];  // 16KB: per-wave h1 exchange

    const int tid = threadIdx.x;

    #pragma unroll
    for (int i = 0; i < 8; ++i) {  // B1 + B2: 2048 16B granules each
        int c = tid + i * 256;
        int row = c >> 4;
        int g = c & 15;
        int dst = row * 128 + (g ^ (row & 15)) * 8;
        int src = row * 128 + g * 8;
        *(uint4*)&B1lds[dst] = *(const uint4*)&Bt1[src];
        *(uint4*)&B2lds[dst] = *(const uint4*)&Bt2[src];
    }
    __syncthreads();  // the only block-wide barrier before the flush

    const int lane = tid & 63;
    const int wid = tid >> 6;
    const int l15 = lane & 15;
    const int quad = lane >> 4;
    unsigned short* X = &Xch[wid * 2048];  // wave-private [16][128]

    float bs1[8], bs2[8];
    #pragma unroll
    for (int n = 0; n < 8; ++n) {
        bs1[n] = bias1[n * 16 + l15];
        bs2[n] = bias2[n * 16 + l15];
    }

    float s[8], q[8];
    #pragma unroll
    for (int n = 0; n < 8; ++n) { s[n] = 0.f; q[n] = 0.f; }

    const int gw = blockIdx.x * 4 + wid;   // global wave id, 0..2047
    for (int grp = gw; grp < N_GROUPS; grp += MLP_WAVES) {
        const int rowBase = grp * 16;      // always fully in-bounds (3125*16=50000)

        // ---- A fragments straight from global (coalesced, L2-hot) ----
        short8 af[4];
        #pragma unroll
        for (int kc = 0; kc < 4; ++kc)
            af[kc] = *(const short8*)&A[(rowBase + l15) * 128 + kc * 32 + quad * 8];

        // ---- GEMM1 ----
        floatx4 acc[8];
        #pragma unroll
        for (int n = 0; n < 8; ++n) acc[n] = (floatx4){0.f, 0.f, 0.f, 0.f};
        #pragma unroll
        for (int kc = 0; kc < 4; ++kc) {
            int ga = (kc * 4 + quad) ^ l15;
            #pragma unroll
            for (int n = 0; n < 8; ++n) {
                short8 bf = *(const short8*)&B1lds[(n * 16 + l15) * 128 + ga * 8];
                acc[n] = __builtin_amdgcn_mfma_f32_16x16x32_bf16(af[kc], bf, acc[n], 0, 0, 0);
            }
        }

        // ---- h1 C-layout -> A-layout via wave-private LDS (no barrier) ----
        #pragma unroll
        for (int n = 0; n < 8; ++n) {
            int col = n * 16 + l15;
            int gg = col >> 3;
            int o7 = col & 7;
            #pragma unroll
            for (int r = 0; r < 4; ++r) {
                int rl = quad * 4 + r;
                float v = fmaxf(acc[n][r] + bs1[n], 0.f);
                X[rl * 128 + ((gg ^ rl) * 8) + o7] = (unsigned short)f2bf(v);
            }
        }
        #pragma unroll
        for (int kc = 0; kc < 4; ++kc)
            af[kc] = *(const short8*)&X[l15 * 128 + (((kc * 4 + quad) ^ l15) * 8)];

        // ---- GEMM2 ----
        #pragma unroll
        for (int n = 0; n < 8; ++n) acc[n] = (floatx4){0.f, 0.f, 0.f, 0.f};
        #pragma unroll
        for (int kc = 0; kc < 4; ++kc) {
            int ga = (kc * 4 + quad) ^ l15;
            #pragma unroll
            for (int n = 0; n < 8; ++n) {
                short8 bf = *(const short8*)&B2lds[(n * 16 + l15) * 128 + ga * 8];
                acc[n] = __builtin_amdgcn_mfma_f32_16x16x32_bf16(af[kc], bf, acc[n], 0, 0, 0);
            }
        }

        // ---- ReLU + y store + BN partials in registers ----
        #pragma unroll
        for (int n = 0; n < 8; ++n) {
            int col = n * 16 + l15;
            #pragma unroll
            for (int r = 0; r < 4; ++r) {
                int row = rowBase + quad * 4 + r;
                float v = fmaxf(acc[n][r] + bs2[n], 0.f);
                yb[row * 128 + col] = (unsigned short)f2bf(v);
                s[n] += v;
                q[n] += v * v;
            }
        }
    }

    // ---- flush BN partials: quad-reduce, block-reduce, one atomic set ----
    #pragma unroll
    for (int n = 0; n < 8; ++n) {
        s[n] += __shfl_xor(s[n], 16);
        s[n] += __shfl_xor(s[n], 32);
        q[n] += __shfl_xor(q[n], 16);
        q[n] += __shfl_xor(q[n], 32);
    }
    __syncthreads();  // all waves done with B1lds; reuse as scratch
    float* red = (float*)B1lds;  // [0..511]=sums [512..1023]=sqs
    if (lane < 16) {
        #pragma unroll
        for (int n = 0; n < 8; ++n) {
            red[wid * 128 + n * 16 + lane] = s[n];
            red[512 + wid * 128 + n * 16 + lane] = q[n];
        }
    }
    __syncthreads();
    float* myStats = stats + (blockIdx.x & (NREP - 1)) * 256;
    if (tid < 128) {
        float ss = 0.f, qq = 0.f;
        #pragma unroll
        for (int w = 0; w < 4; ++w) {
            ss += red[w * 128 + tid];
            qq += red[512 + w * 128 + tid];
        }
        atomicAdd(&myStats[tid], ss);
        atomicAdd(&myStats[128 + tid], qq);
    }
}

// ---------------------------------------------------------------------------
// BatchNorm apply: reduce the 64 stats replicas in-block, precompute
// per-column scale/shift, then o = y*scale + shift. 4 uint4s per thread.
// ---------------------------------------------------------------------------
__global__ __launch_bounds__(256) void bn_kernel(const uint4* __restrict__ yb4,
                                                 float* __restrict__ out,
                                                 const float* __restrict__ stats,
                                                 const float* __restrict__ gamma,
                                                 const float* __restrict__ beta)
{
    __shared__ float red[256];
    __shared__ float sc[128], sh[128];
    int tid = threadIdx.x;

    float acc = 0.f;
    #pragma unroll 8
    for (int r = 0; r < NREP; ++r) acc += stats[r * 256 + tid];
    red[tid] = acc;
    __syncthreads();
    if (tid < 128) {
        const float inv_n = 1.0f / (float)N_NODES;
        float m = red[tid] * inv_n;
        float var = red[128 + tid] * inv_n - m * m;
        float scale = gamma[tid] * rsqrtf(var + BN_EPS);
        sc[tid] = scale;
        sh[tid] = beta[tid] - m * scale;
    }
    __syncthreads();

    const int n8 = N_NODES * D / 8;  // 800000 uint4s
    int base = (blockIdx.x * 256 + tid) * 4;
    #pragma unroll
    for (int i = 0; i < 4; ++i) {
        int idx = base + i;
        if (idx >= n8) break;
        int c0 = (idx << 3) & 127;
        uint4 v = yb4[idx];
        float4 o0, o1;
        o0.x = bflo(v.x) * sc[c0 + 0] + sh[c0 + 0];
        o0.y = bfhi(v.x) * sc[c0 + 1] + sh[c0 + 1];
        o0.z = bflo(v.y) * sc[c0 + 2] + sh[c0 + 2];
        o0.w = bfhi(v.y) * sc[c0 + 3] + sh[c0 + 3];
        o1.x = bflo(v.z) * sc[c0 + 4] + sh[c0 + 4];
        o1.y = bfhi(v.z) * sc[c0 + 5] + sh[c0 + 5];
        o1.z = bflo(v.w) * sc[c0 + 6] + sh[c0 + 6];
        o1.w = bfhi(v.w) * sc[c0 + 7] + sh[c0 + 7];
        ((float4*)out)[idx * 2] = o0;
        ((float4*)out)[idx * 2 + 1] = o1;
    }
}

// ---------------------------------------------------------------------------
extern "C" void kernel_launch(void* const* d_in, const int* in_sizes, int n_in,
                              void* d_out, int out_size, void* d_ws, size_t ws_size,
                              hipStream_t stream) {
    const float* feature = (const float*)d_in[0];
    const int*   ei      = (const int*)d_in[1];
    const float* W1      = (const float*)d_in[2];
    const float* b1      = (const float*)d_in[3];
    const float* W2      = (const float*)d_in[4];
    const float* b2      = (const float*)d_in[5];
    const float* gamma   = (const float*)d_in[6];
    const float* beta    = (const float*)d_in[7];
    float* out = (float*)d_out;

    unsigned*       featb = (unsigned*)d_ws;                        // 12.8 MB
    unsigned*       hb    = featb + N_NODES * 64;                   // 12.8 MB
    unsigned*       yb32  = hb + N_NODES * 64;                      // 12.8 MB
    unsigned short* Wt1   = (unsigned short*)(yb32 + N_NODES * 64); // 32 KB
    unsigned short* Wt2   = Wt1 + D * D;                            // 32 KB
    float*          stats = (float*)(Wt2 + D * D);                  // 64 KB
    int*            cnt   = (int*)(stats + NREP * 256);             // 200 KB
    unsigned short* ssrc  = (unsigned short*)(cnt + N_NODES);       // 6.4 MB buckets
    unsigned short* yb    = (unsigned short*)yb32;

    prep_kernel<<<FEATC_BLOCKS + WPREP_BLOCKS + ZERO_BLOCKS, 256, 0, stream>>>(
        feature, featb, W1, W2, Wt1, Wt2, cnt, stats);
    scatter_kernel<<<(N_EDGES + 255) / 256, 256, 0, stream>>>(ei, cnt, ssrc);
    gather_kernel<<<N_NODES / 4 * 64 / 256, 256, 0, stream>>>(
        (const uint4*)featb, cnt, ssrc, (uint4*)hb);
    mlp_kernel<<<MLP_BLOCKS, 256, 0, stream>>>(
        (const unsigned short*)hb, Wt1, Wt2, b1, b2, yb, stats);
    bn_kernel<<<(N_NODES * D / 8 / 4 + 255) / 256, 256, 0, stream>>>(
        (const uint4*)yb, out, stats, gamma, beta);
}